// Round 1
// 221.453 us; speedup vs baseline: 1.0239x; 1.0239x over previous
//
#include <hip/hip_runtime.h>
#include <stdint.h>

// Problem constants (match reference)
#define T_TOK 1024
#define HDIM  1024
#define IDIM  512
#define NEXP  16
#define ISH   1024       // shared intermediate
#define MAXT128  48      // sum ceil(cnt_e/128) <= 4096/128 + 16 = 48
#define HSLOTS   6144    // 48 * 128 padded routed rows

typedef _Float16 f16;
typedef __attribute__((ext_vector_type(8))) _Float16 f16x8;
typedef __attribute__((ext_vector_type(4))) _Float16 f16x4;
typedef __attribute__((ext_vector_type(4))) float    f32x4;

// ---- async global->LDS, 16B per lane. LDS dst is wave-uniform base; HW adds lane*16.
__device__ __forceinline__ void gld16(const void* g, void* l) {
  __builtin_amdgcn_global_load_lds(
      (__attribute__((address_space(1))) void*)(uintptr_t)g,
      (__attribute__((address_space(3))) void*)(uint32_t)(uintptr_t)l,
      16, 0, 0);
}

// ---- A-tile LDS: rows of 64 halfs, 16B chunks XOR-swizzled by (row&7) (gld16-compatible)
__device__ __forceinline__ f16x8 ldsfragA(const f16* buf, int row, int lch) {
  int phys = lch ^ (row & 7);
  return *(const f16x8*)(buf + row * 64 + phys * 8);
}

// ---- B-tile LDS: n-rows of 64 halfs k-contig, stride 72 f16 (144B, 16B-mult),
// 16B chunk position XOR-swizzled by (n>>3)&7.
__device__ __forceinline__ f16x8 ldsfragB(const f16* buf, int n, int kc) {
  int c = kc ^ ((n >> 3) & 7);
  return *(const f16x8*)(buf + n * 72 + c * 8);
}

// ---- B staging split (T14 issue-early / write-late), 256 threads per matrix.
// loads one 64k x 64n fp32 [K,N] tile into regs
__device__ __forceinline__ void loadB(const float* __restrict__ W, int ldW,
                                      int kt, int n0, int tid2, float2* v) {
  int p = tid2 & 31, kg = tid2 >> 5;            // p: n-pair 0..31, kg: k-oct 0..7
  const float* src = W + (size_t)(kt + 8 * kg) * ldW + n0 + 2 * p;
#pragma unroll
  for (int r = 0; r < 8; r++) v[r] = *(const float2*)(src + (size_t)r * ldW);
}
// cvt fp32->f16 and write swizzled LDS
__device__ __forceinline__ void writeB(f16* __restrict__ Bs, int nbase, int tid2,
                                       const float2* v) {
  int p = tid2 & 31, kg = tid2 >> 5;
  f16x8 c0, c1;
#pragma unroll
  for (int r = 0; r < 8; r++) { c0[r] = (f16)v[r].x; c1[r] = (f16)v[r].y; }
  int nn = nbase + 2 * p;
  int cc = kg ^ ((nn >> 3) & 7);                // nn even -> same chunk for nn+1
  *(f16x8*)(Bs + (size_t)nn * 72 + cc * 8) = c0;
  *(f16x8*)(Bs + (size_t)(nn + 1) * 72 + cc * 8) = c1;
}

// =============== router GEMV (also emits xh = f16(x)): 4 tokens/block ===============
__global__ __launch_bounds__(256) void router_kernel(
    const float* __restrict__ x, const float* __restrict__ rw, const float* __restrict__ ebias,
    f16* __restrict__ xh, int* __restrict__ topk_i, float* __restrict__ topk_w) {
  int wave = threadIdx.x >> 6, l = threadIdx.x & 63;
  int t = blockIdx.x * 4 + wave;
  float acc[16];
#pragma unroll
  for (int e = 0; e < 16; e++) acc[e] = 0.f;
#pragma unroll
  for (int i = 0; i < 4; i++) {
    int k = i * 256 + l * 4;
    float4 xv = *(const float4*)(x + (size_t)t * HDIM + k);
    f16x4 h = { (f16)xv.x, (f16)xv.y, (f16)xv.z, (f16)xv.w };
    *(f16x4*)(xh + (size_t)t * HDIM + k) = h;
    const float* xp = &xv.x;
#pragma unroll
    for (int j = 0; j < 4; j++) {
      float xj = xp[j];
      const float4* w4 = (const float4*)(rw + (size_t)(k + j) * 16);
#pragma unroll
      for (int q = 0; q < 4; q++) {
        float4 w = w4[q];
        acc[q*4+0] += xj * w.x; acc[q*4+1] += xj * w.y;
        acc[q*4+2] += xj * w.z; acc[q*4+3] += xj * w.w;
      }
    }
  }
#pragma unroll
  for (int off = 32; off >= 1; off >>= 1)
#pragma unroll
    for (int e = 0; e < 16; e++) acc[e] += __shfl_xor(acc[e], off, 64);

  if (l == 0) {
    float s[16], sc[16];
#pragma unroll
    for (int e = 0; e < 16; e++) {
      s[e] = 1.f / (1.f + __expf(-acc[e]));       // sigmoid scores (weights)
      sc[e] = s[e] + ebias[e];                     // biased (selection only)
    }
    float gs[4];
#pragma unroll
    for (int g = 0; g < 4; g++) {                  // sum of top-2 per group of 4
      float a = -1e30f, b2 = -1e30f;
#pragma unroll
      for (int j = 0; j < 4; j++) {
        float v = sc[g*4 + j];
        if (v > a) { b2 = a; a = v; } else if (v > b2) { b2 = v; }
      }
      gs[g] = a + b2;
    }
    int g1 = 0;
    for (int g = 1; g < 4; g++) if (gs[g] > gs[g1]) g1 = g;   // ties -> lowest idx
    int g2 = -1;
    for (int g = 0; g < 4; g++) if (g != g1 && (g2 < 0 || gs[g] > gs[g2])) g2 = g;
    float masked[16];
#pragma unroll
    for (int e = 0; e < 16; e++) {
      int g = e >> 2;
      masked[e] = (g == g1 || g == g2) ? sc[e] : 0.0f;        // ref: unselected -> 0.0
    }
    int idx[4]; float wv[4]; float denom = 1e-20f;
#pragma unroll
    for (int j = 0; j < 4; j++) {
      int best = 0; float bv = masked[0];
      for (int e = 1; e < 16; e++) if (masked[e] > bv) { bv = masked[e]; best = e; }
      idx[j] = best; wv[j] = s[best]; denom += s[best];
      masked[best] = -1e30f;
    }
#pragma unroll
    for (int j = 0; j < 4; j++) {
      topk_i[t * 4 + j] = idx[j];
      topk_w[t * 4 + j] = wv[j] / denom * 2.5f;   // fold ROUTED_SCALE
    }
  }
}

// =============== scatter: per-expert lists + 128-row tiles + slot map ===============
__global__ __launch_bounds__(1024) void scatter_kernel(
    const int* __restrict__ tki,
    int* __restrict__ tok, int* __restrict__ slotmap,
    int* __restrict__ tile_e, int* __restrict__ tile_srow,
    int* __restrict__ tile_hb, int* __restrict__ ntl) {
  __shared__ int lcnt[NEXP], lpos[NEXP], lbase[NEXP];
  int t = threadIdx.x;                   // one thread per token
  if (t < NEXP) { lcnt[t] = 0; lpos[t] = 0; }
  __syncthreads();
  int idx[4];
#pragma unroll
  for (int j = 0; j < 4; j++) idx[j] = tki[t*4+j];
#pragma unroll
  for (int j = 0; j < 4; j++) atomicAdd(&lcnt[idx[j]], 1);
  __syncthreads();
  if (t == 0) {                          // tile metadata (tiny serial)
    int total = 0, slots = 0;
    for (int e = 0; e < NEXP; e++) {
      int c = lcnt[e], nt = (c + 127) >> 7;
      lbase[e] = slots;
      for (int j = 0; j < nt; j++) {
        tile_e[total] = e; tile_srow[total] = j * 128; tile_hb[total] = slots + j * 128; total++;
      }
      slots += nt * 128;
    }
    ntl[0] = total;
  }
  __syncthreads();
#pragma unroll
  for (int j = 0; j < 4; j++) {
    int slot = atomicAdd(&lpos[idx[j]], 1);
    tok[idx[j] * T_TOK + slot] = t;
    slotmap[t * 4 + j] = lbase[idx[j]] + slot;   // hbuf/odown row of this assignment
  }
  __syncthreads();
  // padding rows (up to 127/expert) gather token 0; results never read by combine
  int e = t >> 6, s = t & 63;
  int c = lcnt[e];
  int top = ((c + 127) >> 7) << 7;
  for (int s2 = c + s; s2 < top; s2 += 64) tok[e * T_TOK + s2] = 0;
}

// =============== GEMM cores ===============
__device__ __forceinline__ f32x4 mfma16(f16x8 a, f16x8 b, f32x4 c) {
  return __builtin_amdgcn_mfma_f32_16x16x32_f16(a, b, c, 0, 0, 0);
}

// gate+up, TM=128 TN=64 BK=64, 8 waves 4x2 (wave = 32m x 32n), fused silu.
// Double-buffered LDS + prefetch: stage(t+1) issued before compute(t), B writes
// after MFMAs (T14), one barrier per K-step. Waves 0-3 stage gate, 4-7 stage up.
// shared: blocks 0..127; routed gather: blocks 128..511 (48 tiles x 8 nblk)
__global__ __launch_bounds__(512, 4) void gu_all(
    const f16* __restrict__ xh,
    const float* __restrict__ sg, const float* __restrict__ su, f16* __restrict__ hsh,
    const float* __restrict__ wg, const float* __restrict__ wu, f16* __restrict__ hbuf,
    const int* __restrict__ tile_e, const int* __restrict__ tile_srow,
    const int* __restrict__ tile_hb, const int* __restrict__ ntl,
    const int* __restrict__ tok) {
  int b = blockIdx.x;
  const float *Bg, *Bu; f16* Hdst;
  int e = 0, srow = 0, mbase, n0, N;
  bool gather = (b >= 128);
  if (!gather) {
    Bg = sg; Bu = su; Hdst = hsh; N = ISH;
    mbase = (b >> 4) * 128; n0 = (b & 15) * 64;
  } else {
    int rb = b - 128, by = rb >> 3;
    if (by >= ntl[0]) return;
    e = tile_e[by]; srow = tile_srow[by]; mbase = tile_hb[by];
    size_t bo = (size_t)e * HDIM * IDIM;
    Bg = wg + bo; Bu = wu + bo; Hdst = hbuf; N = IDIM;
    n0 = (rb & 7) * 64;
  }
  const int K = HDIM;

  __shared__ f16 As[2 * 128 * 64];                 // 32 KB (2 bufs)
  __shared__ f16 Bgs[2 * 64 * 72], Bus[2 * 64 * 72];  // 18 KB each (2 bufs)

  int tid = threadIdx.x, lane = tid & 63, wave = tid >> 6;
  int quad = lane >> 4, l15 = lane & 15;
  int r = lane >> 3, p = lane & 7;

  // A staging: 16 gld16 oct-groups (rows 0..127), 2 per wave
  const f16* gbA[2]; f16* lbA[2];
#pragma unroll
  for (int jj = 0; jj < 2; jj++) {
    int j = wave * 2 + jj;
    int kcol = (p ^ r) << 3;                       // swizzled k-chunk
    int row = j * 8 + r;
    int grow = gather ? tok[e * T_TOK + srow + row] : (mbase + row);
    gbA[jj] = xh + (size_t)grow * K + kcol;
    lbA[jj] = (f16*)As + (j << 9);
  }

  // B staging: waves 0-3 handle gate, waves 4-7 handle up
  const float* Bmine = (tid < 256) ? Bg : Bu;
  f16* Bsmine = (tid < 256) ? (f16*)Bgs : (f16*)Bus;
  int tid2 = tid & 255;

  int wr = wave >> 1, wc = wave & 1;               // wave tile: 32m x 32n
  f32x4 zero = {0.f, 0.f, 0.f, 0.f};
  f32x4 aG[2][2], aU[2][2];
#pragma unroll
  for (int mi = 0; mi < 2; mi++)
#pragma unroll
    for (int ni = 0; ni < 2; ni++) { aG[mi][ni] = zero; aU[mi][ni] = zero; }

  float2 v[8];
  // prologue: stage kt=0 into buffer 0
#pragma unroll
  for (int jj = 0; jj < 2; jj++) gld16(gbA[jj], lbA[jj]);
  loadB(Bmine, N, 0, n0, tid2, v);
  writeB(Bsmine, 0, tid2, v);
  __syncthreads();

  const int nk = K >> 6;
  for (int it = 0; it < nk; ++it) {
    int cb = it & 1, nb = cb ^ 1;
    bool pf = (it + 1 < nk);
    if (pf) {
      int kt = (it + 1) << 6;
#pragma unroll
      for (int jj = 0; jj < 2; jj++) gld16(gbA[jj] + kt, lbA[jj] + nb * 8192);
      loadB(Bmine, N, kt, n0, tid2, v);            // regs only; wait lands in writeB
    }
    const f16* Ab = (const f16*)As + cb * 8192;
    const f16* Gb = (const f16*)Bgs + cb * 4608;
    const f16* Ub = (const f16*)Bus + cb * 4608;
#pragma unroll
    for (int ks = 0; ks < 2; ks++) {
      int lch = (ks << 2) + quad;
      f16x8 a[2], g[2], u[2];
#pragma unroll
      for (int mi = 0; mi < 2; mi++) a[mi] = ldsfragA(Ab, 32 * wr + 16 * mi + l15, lch);
#pragma unroll
      for (int ni = 0; ni < 2; ni++) {
        g[ni] = ldsfragB(Gb, 32 * wc + 16 * ni + l15, lch);
        u[ni] = ldsfragB(Ub, 32 * wc + 16 * ni + l15, lch);
      }
#pragma unroll
      for (int mi = 0; mi < 2; mi++)
#pragma unroll
        for (int ni = 0; ni < 2; ni++) {
          aG[mi][ni] = mfma16(a[mi], g[ni], aG[mi][ni]);
          aU[mi][ni] = mfma16(a[mi], u[ni], aU[mi][ni]);
        }
    }
    if (pf) writeB(Bsmine + nb * 4608, 0, tid2, v);   // cvt + ds_write after compute
    __syncthreads();
  }
#pragma unroll
  for (int mi = 0; mi < 2; mi++)
#pragma unroll
    for (int ni = 0; ni < 2; ni++)
#pragma unroll
      for (int rg = 0; rg < 4; rg++) {
        int m = 32 * wr + 16 * mi + (quad << 2) + rg;   // C/D: row = quad*4+reg
        int n = n0 + 32 * wc + 16 * ni + l15;           //      col = lane&15
        float g = aG[mi][ni][rg], u = aU[mi][ni][rg];
        float val = (g / (1.f + __expf(-g))) * u;
        Hdst[(size_t)(mbase + m) * N + n] = (f16)val;
      }
}

// down proj, TM=128 TN=128 BK=64, 8 waves 4x2 (wave = 32m x 64n), dbuf+prefetch.
// B staged directly from fp32 [K,H] weights; threads 0-255 stage n-lo, 256-511 n-hi.
// shared: blocks 0..63 -> out fp32; routed: blocks 64..447 -> odown f16
__global__ __launch_bounds__(512, 4) void down_all(
    const f16* __restrict__ hsh, const float* __restrict__ sd,
    const f16* __restrict__ hbuf, const float* __restrict__ wd,
    float* __restrict__ out, f16* __restrict__ odown,
    const int* __restrict__ tile_hb, const int* __restrict__ tile_e,
    const int* __restrict__ ntl) {
  int b = blockIdx.x;
  bool routed = (b >= 64);
  const f16* A; const float* B; int K, abase, n0;
  if (!routed) {
    A = hsh; B = sd; K = ISH;
    abase = (b >> 3) * 128; n0 = (b & 7) * 128;
  } else {
    int rb = b - 64, by = rb >> 3;
    if (by >= ntl[0]) return;
    abase = tile_hb[by];
    A = hbuf; B = wd + (size_t)tile_e[by] * IDIM * HDIM; K = IDIM;
    n0 = (rb & 7) * 128;
  }

  __shared__ f16 As[2 * 128 * 64];     // 32 KB
  __shared__ f16 Bs[2 * 128 * 72];     // 36 KB

  int tid = threadIdx.x, lane = tid & 63, wave = tid >> 6;
  int quad = lane >> 4, l15 = lane & 15;
  int r = lane >> 3, p = lane & 7;

  const f16* gbA[2]; f16* lbA[2];
#pragma unroll
  for (int jj = 0; jj < 2; jj++) {
    int j = wave * 2 + jj;
    int kcol = (p ^ r) << 3;
    int row = j * 8 + r;
    gbA[jj] = A + (size_t)(abase + row) * K + kcol;
    lbA[jj] = (f16*)As + (j << 9);
  }

  int nb0 = (tid < 256) ? 0 : 64;                  // staging n-subtile base
  int tid2 = tid & 255;

  int wr = wave >> 1, wc = wave & 1;               // wave tile: 32m x 64n
  f32x4 zero = {0.f, 0.f, 0.f, 0.f};
  f32x4 ac[2][4];
#pragma unroll
  for (int mi = 0; mi < 2; mi++)
#pragma unroll
    for (int ni = 0; ni < 4; ni++) ac[mi][ni] = zero;

  float2 v[8];
#pragma unroll
  for (int jj = 0; jj < 2; jj++) gld16(gbA[jj], lbA[jj]);
  loadB(B, HDIM, 0, n0 + nb0, tid2, v);
  writeB((f16*)Bs, nb0, tid2, v);
  __syncthreads();

  const int nk = K >> 6;
  for (int it = 0; it < nk; ++it) {
    int cb = it & 1, nb = cb ^ 1;
    bool pf = (it + 1 < nk);
    if (pf) {
      int kt = (it + 1) << 6;
#pragma unroll
      for (int jj = 0; jj < 2; jj++) gld16(gbA[jj] + kt, lbA[jj] + nb * 8192);
      loadB(B, HDIM, kt, n0 + nb0, tid2, v);
    }
    const f16* Ab = (const f16*)As + cb * 8192;
    const f16* Bb = (const f16*)Bs + cb * 9216;
#pragma unroll
    for (int ks = 0; ks < 2; ks++) {
      int lch = (ks << 2) + quad;
      f16x8 a[2], bb[4];
#pragma unroll
      for (int mi = 0; mi < 2; mi++) a[mi] = ldsfragA(Ab, 32 * wr + 16 * mi + l15, lch);
#pragma unroll
      for (int ni = 0; ni < 4; ni++) bb[ni] = ldsfragB(Bb, 64 * wc + 16 * ni + l15, lch);
#pragma unroll
      for (int mi = 0; mi < 2; mi++)
#pragma unroll
        for (int ni = 0; ni < 4; ni++)
          ac[mi][ni] = mfma16(a[mi], bb[ni], ac[mi][ni]);
    }
    if (pf) writeB((f16*)Bs + nb * 9216, nb0, tid2, v);
    __syncthreads();
  }
#pragma unroll
  for (int mi = 0; mi < 2; mi++)
#pragma unroll
    for (int ni = 0; ni < 4; ni++)
#pragma unroll
      for (int rg = 0; rg < 4; rg++) {
        int m = 32 * wr + 16 * mi + (quad << 2) + rg;
        int n = n0 + 64 * wc + 16 * ni + l15;
        if (routed) odown[(size_t)(abase + m) * HDIM + n] = (f16)ac[mi][ni][rg];
        else        out  [(size_t)(abase + m) * HDIM + n] = ac[mi][ni][rg];
      }
}

// =============== combine: out[t] += sum_j w_j * odown[slot(t,j)] ===============
__global__ __launch_bounds__(256) void combine_kernel(
    const f16* __restrict__ odown, const int* __restrict__ slotmap,
    const float* __restrict__ tkw, float* __restrict__ out) {
  int t = blockIdx.x;
  __shared__ int ss[4]; __shared__ float sw[4];
  if (threadIdx.x < 4) {
    ss[threadIdx.x] = slotmap[t * 4 + threadIdx.x];
    sw[threadIdx.x] = tkw[t * 4 + threadIdx.x];
  }
  __syncthreads();
  int h = threadIdx.x * 4;
  float4 acc = *(const float4*)(out + (size_t)t * HDIM + h);
#pragma unroll
  for (int j = 0; j < 4; j++) {
    f16x4 v = *(const f16x4*)(odown + (size_t)ss[j] * HDIM + h);
    float wj = sw[j];
    acc.x += wj * (float)v[0]; acc.y += wj * (float)v[1];
    acc.z += wj * (float)v[2]; acc.w += wj * (float)v[3];
  }
  *(float4*)(out + (size_t)t * HDIM + h) = acc;
}

// =============== launch ===============
extern "C" void kernel_launch(void* const* d_in, const int* in_sizes, int n_in,
                              void* d_out, int out_size, void* d_ws, size_t ws_size,
                              hipStream_t stream) {
  const float* x  = (const float*)d_in[0];
  const float* rw = (const float*)d_in[1];
  const float* eb = (const float*)d_in[2];
  const float* wg = (const float*)d_in[3];
  const float* wu = (const float*)d_in[4];
  const float* wd = (const float*)d_in[5];
  const float* sg = (const float*)d_in[6];
  const float* su = (const float*)d_in[7];
  const float* sd = (const float*)d_in[8];
  float* out = (float*)d_out;
  (void)in_sizes; (void)n_in; (void)out_size; (void)ws_size;

  char* w = (char*)d_ws;
  size_t off = 0;
  auto alloc = [&](size_t b) { void* p = w + off; off = (off + b + 255) & ~(size_t)255; return p; };

  f16* xh   = (f16*)alloc((size_t)T_TOK * HDIM * 2);
  f16* hbuf = (f16*)alloc((size_t)HSLOTS * IDIM * 2);
  f16* hsh  = (f16*)alloc((size_t)T_TOK * ISH * 2);
  f16* odown = (f16*)alloc((size_t)HSLOTS * HDIM * 2);
  int* topk_i = (int*)alloc((size_t)T_TOK * 4 * 4);
  float* topk_w = (float*)alloc((size_t)T_TOK * 4 * 4);
  int* tok  = (int*)alloc((size_t)NEXP * T_TOK * 4);
  int* slotmap = (int*)alloc((size_t)T_TOK * 4 * 4);
  int* tile_e    = (int*)alloc(MAXT128 * 4);
  int* tile_srow = (int*)alloc(MAXT128 * 4);
  int* tile_hb   = (int*)alloc(MAXT128 * 4);
  int* ntl       = (int*)alloc(16);

  router_kernel<<<T_TOK / 4, 256, 0, stream>>>(x, rw, eb, xh, topk_i, topk_w);
  scatter_kernel<<<1, 1024, 0, stream>>>(topk_i, tok, slotmap,
                                         tile_e, tile_srow, tile_hb, ntl);
  // shared gu (128 blocks) + routed gu (384) in one dispatch; B from fp32 weights
  gu_all<<<128 + MAXT128 * 8, 512, 0, stream>>>(
      xh, sg, su, hsh, wg, wu, hbuf, tile_e, tile_srow, tile_hb, ntl, tok);
  // shared down (64) -> out fp32; routed down (384) -> odown f16
  down_all<<<64 + MAXT128 * 8, 512, 0, stream>>>(
      hsh, sd, hbuf, wd, out, odown, tile_hb, tile_e, ntl);
  // out[t] += sum_j w_j * odown[slot]
  combine_kernel<<<T_TOK, 256, 0, stream>>>(odown, slotmap, topk_w, out);
}